// Round 5
// baseline (12277.754 us; speedup 1.0000x reference)
//
#include <hip/hip_runtime.h>
#include <cstdint>
#include <math.h>

// ---------------- problem constants ----------------
#define NSTEPS 64
#define NEGV   (-1.0e9f)

// d_out offsets (in floats): logits[4096][64][128], units[4096][64], ar[4096][1024], sel_num[4096]
#define OUT_L0 0
#define OUT_U0 33554432
#define OUT_A0 33816576
#define OUT_S0 38010880

// d_ws offsets (bytes)
#define WS_KF  0           // float [4096*128*32]  = 67108864 B
#define WS_KA  67108864    // double[4096*32]      = 1048576 B
#define WS_M2  68157440    // float [256*32]       = 32768 B
#define WS_VPB 68222976    // double[256]          = 2048 B

// JAX PRNG mode: 1 = threefry_partitionable (modern default), 0 = legacy split-counter
#define JAX_PARTITIONABLE 1

// ---------------- threefry2x32 (exact JAX algorithm) ----------------
__device__ __forceinline__ uint32_t rotl32(uint32_t x, int r){ return (x << r) | (x >> (32 - r)); }

__device__ __forceinline__ void threefry2x32(uint32_t k0, uint32_t k1,
                                             uint32_t x0, uint32_t x1,
                                             uint32_t &o0, uint32_t &o1){
  const uint32_t ks2 = k0 ^ k1 ^ 0x1BD11BDAu;
  x0 += k0; x1 += k1;
#define TFR(r) { x0 += x1; x1 = rotl32(x1, (r)); x1 ^= x0; }
  TFR(13) TFR(15) TFR(26) TFR(6)
  x0 += k1;  x1 += ks2 + 1u;
  TFR(17) TFR(29) TFR(16) TFR(24)
  x0 += ks2; x1 += k0 + 2u;
  TFR(13) TFR(15) TFR(26) TFR(6)
  x0 += k0;  x1 += k1 + 3u;
  TFR(17) TFR(29) TFR(16) TFR(24)
  x0 += k1;  x1 += ks2 + 4u;
  TFR(13) TFR(15) TFR(26) TFR(6)
  x0 += ks2; x1 += k0 + 5u;
#undef TFR
  o0 = x0; o1 = x1;
}

// bits -> uniform(tiny,1) -> gumbel, mirroring jax's mantissa trick; logs in f64
__device__ __forceinline__ double gumbel_bits(uint32_t bits){
  float f = __uint_as_float(0x3F800000u | (bits >> 9)) - 1.0f;
  float u = (f == 0.0f) ? 1.17549435e-38f : f;
  return -log(-log((double)u));
}

// per-element random bits for step-key (k0,k1), flat index j (B*E = 524288 < 2^32)
__device__ __forceinline__ uint32_t jax_bits(uint32_t k0, uint32_t k1, uint32_t j){
#if JAX_PARTITIONABLE
  uint32_t o0, o1;
  threefry2x32(k0, k1, 0u, j, o0, o1);
  return o0 ^ o1;
#else
  const uint32_t HALF = 262144u;
  uint32_t o0, o1;
  if (j < HALF){ threefry2x32(k0, k1, j, j + HALF, o0, o1); return o0; }
  else         { threefry2x32(k0, k1, j - HALF, j, o0, o1); return o1; }
#endif
}

// ---------------- kernel 1: key_feat[b,e,k] = ee[b,e,:]·conv_w[k,:] + conv_b[k] ----------------
__launch_bounds__(256, 4)
__global__ void k_keyfeat(const float* __restrict__ ee, const float* __restrict__ convw,
                          const float* __restrict__ convb, float* __restrict__ kf){
  __shared__ float wlds[32 * 260];   // conv_w [k][d], row-padded to 260
  __shared__ float elds[8 * 256];    // 8 entity rows
  const int t = threadIdx.x;
  for (int j = 0; j < 32; ++j){
    int idx = t + 256 * j;            // 8192 = 32*256
    int k = idx >> 8, d = idx & 255;
    wlds[k * 260 + d] = convw[idx];
  }
  __syncthreads();
  const int r8 = t >> 5, k = t & 31;
  const float bk = convb[k];
  const long rowbase = (long)blockIdx.x * 256;
  for (int it = 0; it < 32; ++it){
    long r0 = rowbase + it * 8;
    #pragma unroll
    for (int j = 0; j < 2; ++j){
      int f = t + 256 * j;            // 512 float4s
      int rr = f >> 6, d4 = (f & 63) << 2;
      *reinterpret_cast<float4*>(&elds[rr * 256 + d4]) =
        *reinterpret_cast<const float4*>(&ee[(r0 + rr) * 256 + d4]);
    }
    __syncthreads();
    float c0 = 0.f, c1 = 0.f, c2 = 0.f, c3 = 0.f;
    #pragma unroll 8
    for (int d4 = 0; d4 < 256; d4 += 4){
      float4 e4 = *reinterpret_cast<const float4*>(&elds[r8 * 256 + d4]);
      float4 w4 = *reinterpret_cast<const float4*>(&wlds[k * 260 + d4]);
      c0 = fmaf(e4.x, w4.x, c0); c1 = fmaf(e4.y, w4.y, c1);
      c2 = fmaf(e4.z, w4.z, c2); c3 = fmaf(e4.w, w4.w, c3);
    }
    double s = ((double)c0 + (double)c1) + ((double)c2 + (double)c3) + (double)bk;
    kf[(r0 + r8) * 32 + k] = (float)s;
    __syncthreads();
  }
}

// ---------------- kernel 2: key_avg[b,k] = sum_e kf / unit_num[b] (f64) ----------------
__global__ void k_keyavg(const float* __restrict__ kf, const float* __restrict__ unum,
                         double* __restrict__ ka){
  const int t = threadIdx.x;
  const int b = blockIdx.x * 8 + (t >> 5), k = t & 31;
  const float* p = kf + (long)b * 4096 + k;
  double s = 0.0;
  #pragma unroll 8
  for (int e = 0; e < 128; ++e) s += (double)p[e * 32];
  ka[b * 32 + k] = s / (double)unum[b];
}

// ---------------- kernel 3: M2 = fc1_w @ proj_w (f32 out), v_pb = fc1_w @ proj_b (f64) ----------------
__global__ void k_m2(const float* __restrict__ fc1w, const float* __restrict__ projw,
                     const float* __restrict__ projb, float* __restrict__ m2,
                     double* __restrict__ vpb){
  const int t = threadIdx.x;
  if (blockIdx.x < 32){
    const int o = blockIdx.x * 8 + (t >> 5), k = t & 31;
    double s = 0.0;
    for (int d = 0; d < 1024; ++d)
      s = fma((double)fc1w[o * 1024 + d], (double)projw[d * 32 + k], s);
    m2[o * 32 + k] = (float)s;
  } else {
    const int o = t;
    double s = 0.0;
    for (int d = 0; d < 1024; ++d)
      s = fma((double)fc1w[o * 1024 + d], (double)projb[d], s);
    vpb[o] = s;
  }
}

// ---------------- scan kernel: 512 threads, 4 rows/block, 2 blocks/CU, 3 barriers/step ----
// w_ih regs/thread = 32768/512 = 64 f32 (the T=256 variant spilled; T=512 is mandatory).
// LDS layout (bytes):
#define SM_KF   0        // float [4][4224]  kf rows e*33+k (pad-33)   67584
#define SM_X    67584    // float [4][288]   chunked-36 relu(z)         4608
#define SM_GL   72192    // double[4][128]   gates                      4096
#define SM_HF   76288    // float [4][32]    h (f32 validated R4)        512
#define SM_OV   76800    // double[4][32]    epilogue sacc              1024
#define SM_OVF  77824    // float [4][32]    out vec for G               512
#define SM_KA2  78336    // double[4][32]    key_avg                    1024
#define SM_KEYS 79360    // uint2 [64]                                   512
#define SM_GT   79872    // float [4]        gate flags                   16
#define SM_CNT  79888    // double[4]        counts                       32
#define SM_SIZE 79920    // x2 = 159840 <= 163840 -> 2 blocks/CU

__launch_bounds__(512, 4)
__global__ void k_scan(const float* __restrict__ ar0, const void* __restrict__ selmask,
                       const float* __restrict__ fc1w, const float* __restrict__ fc1b,
                       const float* __restrict__ wih, const float* __restrict__ whh,
                       const float* __restrict__ bih, const float* __restrict__ bhh,
                       const float* __restrict__ projw, const float* __restrict__ projb,
                       const float* __restrict__ kfg, const double* __restrict__ kag,
                       const float* __restrict__ m2f, const double* __restrict__ vpbg,
                       float* __restrict__ outp){
  extern __shared__ char smem[];
  float*  kfp = (float*) (smem + SM_KF);
  float*  xk  = (float*) (smem + SM_X);
  double* gl  = (double*)(smem + SM_GL);
  float*  hf  = (float*) (smem + SM_HF);
  double* ovd = (double*)(smem + SM_OV);
  float*  ovf = (float*) (smem + SM_OVF);
  double* kav = (double*)(smem + SM_KA2);
  uint2*  keys= (uint2*) (smem + SM_KEYS);
  float*  gtf = (float*) (smem + SM_GT);
  double* cntd= (double*)(smem + SM_CNT);

  const int t  = threadIdx.x;         // 0..511
  const int w  = t >> 6;              // wave 0..7; waves 0..3 own row w
  const int ln = t & 63;
  const int o  = t & 255;             // column owner for z/x/G
  const int rh = t >> 8;              // row pair selector: rows rh*2+q
  const int g  = t >> 2;              // gate 0..127
  const int sh = t & 3;               // d-quarter
  const long blkrow = (long)blockIdx.x * 4;

  // step keys: key_i = threefry((0,42),(0,i))
  if (t < NSTEPS){
    uint32_t o0, o1; threefry2x32(0u, 42u, 0u, (uint32_t)t, o0, o1);
    keys[t] = make_uint2(o0, o1);
  }
  // stage ar0 rows into kf area (reused before kf load)
  float* arst = (float*)(smem + SM_KF);   // [4][1024]
  #pragma unroll
  for (int j = 0; j < 2; ++j){            // 1024 float4
    int f = t + 512 * j;
    int r = f >> 8, d4 = (f & 255) << 2;
    *reinterpret_cast<float4*>(&arst[r * 1024 + d4]) =
      *reinterpret_cast<const float4*>(&ar0[(blkrow + r) * 1024 + d4]);
  }
  if (t < 128) kav[t] = kag[blkrow * 32 + t];
  __syncthreads();

  // z0[rh*2+q][o] = fc1_w[o,:]·ar0 + fc1_b[o]   (f32 chains, f64 combine)
  double z[2];
  {
    float a[2][4] = {{0.f,0.f,0.f,0.f},{0.f,0.f,0.f,0.f}};
    const float* wr = fc1w + (long)o * 1024;
    #pragma unroll 4
    for (int d4 = 0; d4 < 1024; d4 += 4){
      float4 w4 = *reinterpret_cast<const float4*>(&wr[d4]);
      #pragma unroll
      for (int q = 0; q < 2; ++q){
        float4 av = *reinterpret_cast<const float4*>(&arst[(rh * 2 + q) * 1024 + d4]);
        a[q][0] = fmaf(w4.x, av.x, a[q][0]); a[q][1] = fmaf(w4.y, av.y, a[q][1]);
        a[q][2] = fmaf(w4.z, av.z, a[q][2]); a[q][3] = fmaf(w4.w, av.w, a[q][3]);
      }
    }
    const double bb = (double)fc1b[o];
    #pragma unroll
    for (int q = 0; q < 2; ++q)
      z[q] = ((double)a[q][0] + (double)a[q][1]) + ((double)a[q][2] + (double)a[q][3]) + bb;
  }
  __syncthreads();   // arst reads done before kf staging overwrites

  // stage kf rows, pad-33: kfp[r*4224 + e*33 + k]  (2-way banks everywhere: free)
  #pragma unroll
  for (int it = 0; it < 8; ++it){
    int f = t + 512 * it;                // 4096 float4
    int r = f >> 10, rem = f & 1023;
    int e = rem >> 3, kq = rem & 7;
    float4 v = *reinterpret_cast<const float4*>(
        &kfg[(size_t)((blkrow + r) * 128 + e) * 32 + kq * 4]);
    float* dst = &kfp[r * 4224 + e * 33 + kq * 4];
    dst[0] = v.x; dst[1] = v.y; dst[2] = v.z; dst[3] = v.w;
  }

  // register preloads: w_ih quarter (64 f32), w_hh quarter, bias. NO m2 in regs.
  float4 w4r[16];
  #pragma unroll
  for (int i4 = 0; i4 < 16; ++i4)
    w4r[i4] = *reinterpret_cast<const float4*>(&wih[g * 256 + sh * 64 + i4 * 4]);
  float whr[8];
  #pragma unroll
  for (int jk = 0; jk < 8; ++jk) whr[jk] = whh[g * 32 + sh * 8 + jk];
  const double bsum = (double)bih[g] + (double)bhh[g];
  const double vpbr = vpbg[o];

  // ---- mask load with dtype auto-detect (bool as u8 bytes vs 32-bit words) ----
  uint64_t m0, m1;
  {
    const uint32_t w0 = *(const uint32_t*)selmask;
    if (w0 == 0x01010101u){
      const uint8_t* m8 = (const uint8_t*)selmask;
      m0 = __ballot(m8[(blkrow + (w & 3)) * 128 + ln] != 0);
      m1 = __ballot(m8[(blkrow + (w & 3)) * 128 + 64 + ln] != 0);
    } else {
      const uint32_t* m32 = (const uint32_t*)selmask;
      m0 = __ballot(m32[(blkrow + (w & 3)) * 128 + ln] != 0);
      m1 = __ballot(m32[(blkrow + (w & 3)) * 128 + 64 + ln] != 0);
    }
  }
  bool  isend = false;
  float selnum = (float)NSTEPS;          // wave w<4, ln==0
  double cnt_reg = 0.0;                  // wave w<4, ln==0
  double c_reg = 0.0, sacc_reg = 0.0;    // wave w<4, lanes<32 (k=ln)
  if (t < 128) hf[t] = 0.f;
  __syncthreads();

  #pragma unroll 1
  for (int i = 0; i < NSTEPS; ++i){
    // --- A: x = relu(z) -> LDS (f32, reference's own quantization point) ---
    #pragma unroll
    for (int q = 0; q < 2; ++q){
      double zv = z[q];
      float xv = zv > 0.0 ? (float)zv : 0.0f;
      xk[(rh * 2 + q) * 288 + (o >> 5) * 36 + (o & 31)] = xv;
    }
    __syncthreads();                                  // bar1: xk ready

    // --- B: gates (all 8 waves; 1 gate x 64-d quarter; f32 chains, f64 combine) ---
    {
      float acc[4]  = {0.f,0.f,0.f,0.f};
      float hacc[4] = {0.f,0.f,0.f,0.f};
      #pragma unroll
      for (int i4 = 0; i4 < 16; ++i4){
        const int xi = (sh * 2 + (i4 >> 3)) * 36 + (i4 & 7) * 4;
        const float4 w4 = w4r[i4];
        #pragma unroll
        for (int r = 0; r < 4; ++r){
          float4 xv = *reinterpret_cast<const float4*>(&xk[r * 288 + xi]);
          acc[r] = fmaf(w4.x, xv.x, fmaf(w4.y, xv.y,
                   fmaf(w4.z, xv.z, fmaf(w4.w, xv.w, acc[r]))));
        }
      }
      #pragma unroll
      for (int q2 = 0; q2 < 2; ++q2){
        const float* wp = &whr[q2 * 4];
        #pragma unroll
        for (int r = 0; r < 4; ++r){
          float4 hv = *reinterpret_cast<const float4*>(&hf[r * 32 + sh * 8 + q2 * 4]);
          hacc[r] = fmaf(wp[0], hv.x, fmaf(wp[1], hv.y,
                    fmaf(wp[2], hv.z, fmaf(wp[3], hv.w, hacc[r]))));
        }
      }
      #pragma unroll
      for (int r = 0; r < 4; ++r){
        double tot = (double)acc[r] + (double)hacc[r];
        tot += __shfl_xor(tot, 1);
        tot += __shfl_xor(tot, 2);
        if (sh == 0) gl[r * 128 + g] = tot + bsum;
      }
    }
    __syncthreads();                                  // bar2: gl ready

    // --- waves 0..3: C/D/E/F for row w (wave-local; waves 4..7 go to bar3) ---
    if (w < 4){
      // C: LSTM pointwise (lanes<32; f64 internal, h published f32 — R4-validated)
      if (ln < 32){
        const int k = ln;
        double gi = gl[w * 128 + k],      gf = gl[w * 128 + 32 + k];
        double gc = gl[w * 128 + 64 + k], go = gl[w * 128 + 96 + k];
        double ig = 1.0 / (1.0 + exp(-gi));
        double fg = 1.0 / (1.0 + exp(-gf));
        double og = 1.0 / (1.0 + exp(-go));
        c_reg = fg * c_reg + ig * tanh(gc);
        hf[w * 32 + k] = (float)(og * tanh(c_reg));
      }
      asm volatile("s_waitcnt lgkmcnt(0)" ::: "memory");
      __builtin_amdgcn_sched_barrier(0);

      // D: logits (f64 split chains; pad-33 b32 reads conflict-free)
      double lg[2];
      const size_t lbase = ((size_t)(blkrow + w) * NSTEPS + i) * 128;
      #pragma unroll
      for (int j = 0; j < 2; ++j){
        const int e = ln + 64 * j;
        const float* kr = &kfp[w * 4224 + e * 33];
        double a0 = 0.0, a1 = 0.0;
        #pragma unroll
        for (int k4 = 0; k4 < 8; ++k4){
          float4 hv = *reinterpret_cast<const float4*>(&hf[w * 32 + k4 * 4]);  // uniform
          a0 = fma((double)kr[k4 * 4 + 0], (double)hv.x, a0);
          a1 = fma((double)kr[k4 * 4 + 1], (double)hv.y, a1);
          a0 = fma((double)kr[k4 * 4 + 2], (double)hv.z, a0);
          a1 = fma((double)kr[k4 * 4 + 3], (double)hv.w, a1);
        }
        lg[j] = a0 + a1;
        bool bit = (j == 0) ? ((m0 >> e) & 1ull) : ((m1 >> (e - 64)) & 1ull);
        outp[OUT_L0 + lbase + e] = bit ? (float)lg[j] : NEGV;
      }

      // E: gumbel-argmax (exact threefry; masked lanes can't win)
      double bs = -1.0e300; int bi = 1 << 20;
      {
        const uint2 kk = keys[i];
        #pragma unroll
        for (int j = 0; j < 2; ++j){
          const int e = ln + 64 * j;
          bool bit = (j == 0) ? ((m0 >> e) & 1ull) : ((m1 >> (e - 64)) & 1ull);
          if (bit){
            uint32_t bits = jax_bits(kk.x, kk.y, (uint32_t)((blkrow + w) * 128 + e));
            double sv = lg[j] + gumbel_bits(bits);
            if (sv > bs || (sv == bs && e < bi)){ bs = sv; bi = e; }
          }
        }
      }
      #pragma unroll
      for (int m = 1; m < 64; m <<= 1){
        double os = __shfl_xor(bs, m);
        int    oi = __shfl_xor(bi, m);
        if (os > bs || (os == bs && oi < bi)){ bs = os; bi = oi; }
      }
      const int uid = bi;

      // F: state updates (wave-local)
      {
        const bool new_end = (uid == 127);
        if (ln == 0 && new_end && !isend) selnum = (float)i;
        isend = isend || new_end;
        const double gate = isend ? 0.0 : 1.0;
        if (uid < 64) m0 &= ~(1ull << uid); else m1 &= ~(1ull << (uid - 64));
        if (ln == 0){
          gtf[w] = (float)gate;
          cnt_reg += gate;
          outp[OUT_U0 + (size_t)(blkrow + w) * NSTEPS + i] = (float)uid;
        }
        if (ln < 32){
          const int k = ln;
          float kv = kfp[w * 4224 + uid * 33 + k];
          double ov = (double)kv - kav[w * 32 + k];
          ovf[w * 32 + k] = (float)ov;
          sacc_reg += gate * ov;
        }
      }
    }
    __syncthreads();                                  // bar3: ovf/gtf ready

    // --- G: z += gate*(M2[o,:]·out + v_pb[o])  (f32 delta, f64 carry — R4-validated)
    //     m2 read from global each step: block footprint = 32 KB = L1-resident.
    //     Pointer laundering stops LICM from hoisting 32 VGPRs of m2 into the loop.
    {
      const float* mp = m2f + o * 32;
      asm volatile("" : "+v"(mp));      // opaque -> loads stay inside the loop
      float zf0 = 0.f, zf1 = 0.f;
      const int r0 = rh * 2, r1 = rh * 2 + 1;
      #pragma unroll
      for (int j8 = 0; j8 < 8; ++j8){
        float4 mr  = *reinterpret_cast<const float4*>(&mp[j8 * 4]);
        float4 ov0 = *reinterpret_cast<const float4*>(&ovf[r0 * 32 + j8 * 4]);  // uniform
        float4 ov1 = *reinterpret_cast<const float4*>(&ovf[r1 * 32 + j8 * 4]);  // uniform
        zf0 = fmaf(mr.x, ov0.x, fmaf(mr.y, ov0.y, fmaf(mr.z, ov0.z, fmaf(mr.w, ov0.w, zf0))));
        zf1 = fmaf(mr.x, ov1.x, fmaf(mr.y, ov1.y, fmaf(mr.z, ov1.z, fmaf(mr.w, ov1.w, zf1))));
      }
      if (gtf[r0] != 0.f) z[0] += (double)zf0 + vpbr;
      if (gtf[r1] != 0.f) z[1] += (double)zf1 + vpbr;
    }
    // no barrier: A(i+1) writes xk; all waves finished B(i) before bar2(i)<bar3(i).
  }

  // -------- epilogue: sel_num, s_acc publish, final ar --------
  __syncthreads();
  if (w < 4 && ln < 32) ovd[w * 32 + ln] = sacc_reg;
  if (w < 4 && ln == 0){
    cntd[w] = cnt_reg;
    outp[OUT_S0 + (blkrow + w)] = selnum;
  }
  __syncthreads();

  #pragma unroll
  for (int jj = 0; jj < 2; ++jj){
    const int dd = jj * 512 + t;
    float4 pw4[8];
    #pragma unroll
    for (int q = 0; q < 8; ++q)
      pw4[q] = *reinterpret_cast<const float4*>(&projw[dd * 32 + q * 4]);
    const double pb = (double)projb[dd];
    #pragma unroll
    for (int r = 0; r < 4; ++r){
      const double* sp = &ovd[r * 32];
      double acc = 0.0;
      #pragma unroll
      for (int q = 0; q < 8; ++q){
        acc = fma((double)pw4[q].x, sp[q * 4 + 0], acc);
        acc = fma((double)pw4[q].y, sp[q * 4 + 1], acc);
        acc = fma((double)pw4[q].z, sp[q * 4 + 2], acc);
        acc = fma((double)pw4[q].w, sp[q * 4 + 3], acc);
      }
      double arv = (double)ar0[(blkrow + r) * 1024 + dd] + acc + pb * cntd[r];
      outp[OUT_A0 + (size_t)(blkrow + r) * 1024 + dd] = (float)arv;
    }
  }
}

// ---------------- launcher ----------------
extern "C" void kernel_launch(void* const* d_in, const int* in_sizes, int n_in,
                              void* d_out, int out_size, void* d_ws, size_t ws_size,
                              hipStream_t stream){
  const float*   ar0   = (const float*)d_in[0];
  const float*   ee    = (const float*)d_in[1];
  const void*    msk   = (const void*)d_in[2];
  const float*   unum  = (const float*)d_in[3];
  const float*   convw = (const float*)d_in[4];
  const float*   convb = (const float*)d_in[5];
  const float*   fc1w  = (const float*)d_in[6];
  const float*   fc1b  = (const float*)d_in[7];
  const float*   wih   = (const float*)d_in[8];
  const float*   whh   = (const float*)d_in[9];
  const float*   bih   = (const float*)d_in[10];
  const float*   bhh   = (const float*)d_in[11];
  const float*   projw = (const float*)d_in[12];
  const float*   projb = (const float*)d_in[13];
  float* out = (float*)d_out;
  char*  ws  = (char*)d_ws;

  float*  kf  = (float*) (ws + WS_KF);
  double* ka  = (double*)(ws + WS_KA);
  float*  m2  = (float*) (ws + WS_M2);
  double* vpb = (double*)(ws + WS_VPB);

  k_keyfeat<<<2048, 256, 0, stream>>>(ee, convw, convb, kf);
  k_keyavg <<<512, 256, 0, stream>>>(kf, unum, ka);
  k_m2     <<<33, 256, 0, stream>>>(fc1w, projw, projb, m2, vpb);

  (void)hipFuncSetAttribute((const void*)k_scan,
                            hipFuncAttributeMaxDynamicSharedMemorySize, SM_SIZE);
  k_scan<<<1024, 512, SM_SIZE, stream>>>(ar0, msk, fc1w, fc1b, wih, whh, bih, bhh,
                                         projw, projb, kf, ka, m2, vpb, out);
}

// Round 6
// 6665.695 us; speedup vs baseline: 1.8419x; 1.8419x over previous
//
#include <hip/hip_runtime.h>
#include <cstdint>
#include <math.h>

// ---------------- problem constants ----------------
#define NSTEPS 64
#define NEGV   (-1.0e9f)

// d_out offsets (in floats): logits[4096][64][128], units[4096][64], ar[4096][1024], sel_num[4096]
#define OUT_L0 0
#define OUT_U0 33554432
#define OUT_A0 33816576
#define OUT_S0 38010880

// d_ws offsets (bytes)
#define WS_KF  0           // float [4096*128*32]  = 67108864 B
#define WS_KA  67108864    // double[4096*32]      = 1048576 B
#define WS_M2  68157440    // float [256*32]       = 32768 B
#define WS_VPB 68222976    // double[256]          = 2048 B

// JAX PRNG mode: 1 = threefry_partitionable (modern default), 0 = legacy split-counter
#define JAX_PARTITIONABLE 1

// ---------------- threefry2x32 (exact JAX algorithm) ----------------
__device__ __forceinline__ uint32_t rotl32(uint32_t x, int r){ return (x << r) | (x >> (32 - r)); }

__device__ __forceinline__ void threefry2x32(uint32_t k0, uint32_t k1,
                                             uint32_t x0, uint32_t x1,
                                             uint32_t &o0, uint32_t &o1){
  const uint32_t ks2 = k0 ^ k1 ^ 0x1BD11BDAu;
  x0 += k0; x1 += k1;
#define TFR(r) { x0 += x1; x1 = rotl32(x1, (r)); x1 ^= x0; }
  TFR(13) TFR(15) TFR(26) TFR(6)
  x0 += k1;  x1 += ks2 + 1u;
  TFR(17) TFR(29) TFR(16) TFR(24)
  x0 += ks2; x1 += k0 + 2u;
  TFR(13) TFR(15) TFR(26) TFR(6)
  x0 += k0;  x1 += k1 + 3u;
  TFR(17) TFR(29) TFR(16) TFR(24)
  x0 += k1;  x1 += ks2 + 4u;
  TFR(13) TFR(15) TFR(26) TFR(6)
  x0 += ks2; x1 += k0 + 5u;
#undef TFR
  o0 = x0; o1 = x1;
}

// bits -> uniform(tiny,1) -> gumbel, mirroring jax's mantissa trick; logs in f64
__device__ __forceinline__ double gumbel_bits(uint32_t bits){
  float f = __uint_as_float(0x3F800000u | (bits >> 9)) - 1.0f;
  float u = (f == 0.0f) ? 1.17549435e-38f : f;
  return -log(-log((double)u));
}

// per-element random bits for step-key (k0,k1), flat index j (B*E = 524288 < 2^32)
__device__ __forceinline__ uint32_t jax_bits(uint32_t k0, uint32_t k1, uint32_t j){
#if JAX_PARTITIONABLE
  uint32_t o0, o1;
  threefry2x32(k0, k1, 0u, j, o0, o1);
  return o0 ^ o1;
#else
  const uint32_t HALF = 262144u;
  uint32_t o0, o1;
  if (j < HALF){ threefry2x32(k0, k1, j, j + HALF, o0, o1); return o0; }
  else         { threefry2x32(k0, k1, j - HALF, j, o0, o1); return o1; }
#endif
}

// ---------------- kernel 1: key_feat[b,e,k] = ee[b,e,:]·conv_w[k,:] + conv_b[k] ----------------
__launch_bounds__(256, 4)
__global__ void k_keyfeat(const float* __restrict__ ee, const float* __restrict__ convw,
                          const float* __restrict__ convb, float* __restrict__ kf){
  __shared__ float wlds[32 * 260];   // conv_w [k][d], row-padded to 260
  __shared__ float elds[8 * 256];    // 8 entity rows
  const int t = threadIdx.x;
  for (int j = 0; j < 32; ++j){
    int idx = t + 256 * j;            // 8192 = 32*256
    int k = idx >> 8, d = idx & 255;
    wlds[k * 260 + d] = convw[idx];
  }
  __syncthreads();
  const int r8 = t >> 5, k = t & 31;
  const float bk = convb[k];
  const long rowbase = (long)blockIdx.x * 256;
  for (int it = 0; it < 32; ++it){
    long r0 = rowbase + it * 8;
    #pragma unroll
    for (int j = 0; j < 2; ++j){
      int f = t + 256 * j;            // 512 float4s
      int rr = f >> 6, d4 = (f & 63) << 2;
      *reinterpret_cast<float4*>(&elds[rr * 256 + d4]) =
        *reinterpret_cast<const float4*>(&ee[(r0 + rr) * 256 + d4]);
    }
    __syncthreads();
    float c0 = 0.f, c1 = 0.f, c2 = 0.f, c3 = 0.f;
    #pragma unroll 8
    for (int d4 = 0; d4 < 256; d4 += 4){
      float4 e4 = *reinterpret_cast<const float4*>(&elds[r8 * 256 + d4]);
      float4 w4 = *reinterpret_cast<const float4*>(&wlds[k * 260 + d4]);
      c0 = fmaf(e4.x, w4.x, c0); c1 = fmaf(e4.y, w4.y, c1);
      c2 = fmaf(e4.z, w4.z, c2); c3 = fmaf(e4.w, w4.w, c3);
    }
    double s = ((double)c0 + (double)c1) + ((double)c2 + (double)c3) + (double)bk;
    kf[(r0 + r8) * 32 + k] = (float)s;
    __syncthreads();
  }
}

// ---------------- kernel 2: key_avg[b,k] = sum_e kf / unit_num[b] (f64) ----------------
__global__ void k_keyavg(const float* __restrict__ kf, const float* __restrict__ unum,
                         double* __restrict__ ka){
  const int t = threadIdx.x;
  const int b = blockIdx.x * 8 + (t >> 5), k = t & 31;
  const float* p = kf + (long)b * 4096 + k;
  double s = 0.0;
  #pragma unroll 8
  for (int e = 0; e < 128; ++e) s += (double)p[e * 32];
  ka[b * 32 + k] = s / (double)unum[b];
}

// ---------------- kernel 3: M2 = fc1_w @ proj_w (f32 out), v_pb = fc1_w @ proj_b (f64) ----------------
__global__ void k_m2(const float* __restrict__ fc1w, const float* __restrict__ projw,
                     const float* __restrict__ projb, float* __restrict__ m2,
                     double* __restrict__ vpb){
  const int t = threadIdx.x;
  if (blockIdx.x < 32){
    const int o = blockIdx.x * 8 + (t >> 5), k = t & 31;
    double s = 0.0;
    for (int d = 0; d < 1024; ++d)
      s = fma((double)fc1w[o * 1024 + d], (double)projw[d * 32 + k], s);
    m2[o * 32 + k] = (float)s;
  } else {
    const int o = t;
    double s = 0.0;
    for (int d = 0; d < 1024; ++d)
      s = fma((double)fc1w[o * 1024 + d], (double)projb[d], s);
    vpb[o] = s;
  }
}

// ---------------- scan kernel: 512 threads, 4 rows/block, 3 barriers/step ----------------
// LAUNCH BOUNDS LAW (measured R2/R5): arg2=2 -> 128-VGPR cap (fits, no spill);
// arg2=4 -> 64-VGPR cap (w4r alone is 64 -> catastrophic spill, 41 GB scratch).
// At 128 VGPR the HW still allows 4 waves/SIMD -> 2 blocks/CU with 79.9 KB LDS.
// LDS layout (bytes):
#define SM_KF   0        // float [4][4224]  kf rows e*33+k (pad-33)   67584
#define SM_X    67584    // float [4][288]   chunked-36 relu(z)         4608
#define SM_GL   72192    // double[4][128]   gates                      4096
#define SM_HF   76288    // float [4][32]    h (f32 validated R4)        512
#define SM_OV   76800    // double[4][32]    epilogue sacc              1024
#define SM_OVF  77824    // float [4][32]    out vec for G               512
#define SM_KA2  78336    // double[4][32]    key_avg                    1024
#define SM_KEYS 79360    // uint2 [64]                                   512
#define SM_GT   79872    // float [4]        gate flags                   16
#define SM_CNT  79888    // double[4]        counts                       32
#define SM_SIZE 79920    // x2 = 159840 <= 163840 -> 2 blocks/CU

__launch_bounds__(512, 2)
__global__ void k_scan(const float* __restrict__ ar0, const void* __restrict__ selmask,
                       const float* __restrict__ fc1w, const float* __restrict__ fc1b,
                       const float* __restrict__ wih, const float* __restrict__ whh,
                       const float* __restrict__ bih, const float* __restrict__ bhh,
                       const float* __restrict__ projw, const float* __restrict__ projb,
                       const float* __restrict__ kfg, const double* __restrict__ kag,
                       const float* __restrict__ m2f, const double* __restrict__ vpbg,
                       float* __restrict__ outp){
  extern __shared__ char smem[];
  float*  kfp = (float*) (smem + SM_KF);
  float*  xk  = (float*) (smem + SM_X);
  double* gl  = (double*)(smem + SM_GL);
  float*  hf  = (float*) (smem + SM_HF);
  double* ovd = (double*)(smem + SM_OV);
  float*  ovf = (float*) (smem + SM_OVF);
  double* kav = (double*)(smem + SM_KA2);
  uint2*  keys= (uint2*) (smem + SM_KEYS);
  float*  gtf = (float*) (smem + SM_GT);
  double* cntd= (double*)(smem + SM_CNT);

  const int t  = threadIdx.x;         // 0..511
  const int w  = t >> 6;              // wave 0..7; waves 0..3 own row w
  const int ln = t & 63;
  const int o  = t & 255;             // column owner for z/x/G
  const int rh = t >> 8;              // row pair selector: rows rh*2+q
  const int g  = t >> 2;              // gate 0..127
  const int sh = t & 3;               // d-quarter
  const long blkrow = (long)blockIdx.x * 4;

  // step keys: key_i = threefry((0,42),(0,i))
  if (t < NSTEPS){
    uint32_t o0, o1; threefry2x32(0u, 42u, 0u, (uint32_t)t, o0, o1);
    keys[t] = make_uint2(o0, o1);
  }
  // stage ar0 rows into kf area (reused before kf load)
  float* arst = (float*)(smem + SM_KF);   // [4][1024]
  #pragma unroll
  for (int j = 0; j < 2; ++j){            // 1024 float4
    int f = t + 512 * j;
    int r = f >> 8, d4 = (f & 255) << 2;
    *reinterpret_cast<float4*>(&arst[r * 1024 + d4]) =
      *reinterpret_cast<const float4*>(&ar0[(blkrow + r) * 1024 + d4]);
  }
  if (t < 128) kav[t] = kag[blkrow * 32 + t];
  __syncthreads();

  // z0[rh*2+q][o] = fc1_w[o,:]·ar0 + fc1_b[o]   (f32 chains, f64 combine)
  double z[2];
  {
    float a[2][4] = {{0.f,0.f,0.f,0.f},{0.f,0.f,0.f,0.f}};
    const float* wr = fc1w + (long)o * 1024;
    #pragma unroll 4
    for (int d4 = 0; d4 < 1024; d4 += 4){
      float4 w4 = *reinterpret_cast<const float4*>(&wr[d4]);
      #pragma unroll
      for (int q = 0; q < 2; ++q){
        float4 av = *reinterpret_cast<const float4*>(&arst[(rh * 2 + q) * 1024 + d4]);
        a[q][0] = fmaf(w4.x, av.x, a[q][0]); a[q][1] = fmaf(w4.y, av.y, a[q][1]);
        a[q][2] = fmaf(w4.z, av.z, a[q][2]); a[q][3] = fmaf(w4.w, av.w, a[q][3]);
      }
    }
    const double bb = (double)fc1b[o];
    #pragma unroll
    for (int q = 0; q < 2; ++q)
      z[q] = ((double)a[q][0] + (double)a[q][1]) + ((double)a[q][2] + (double)a[q][3]) + bb;
  }
  __syncthreads();   // arst reads done before kf staging overwrites

  // stage kf rows, pad-33: kfp[r*4224 + e*33 + k]  (2-way banks everywhere: free)
  #pragma unroll
  for (int it = 0; it < 8; ++it){
    int f = t + 512 * it;                // 4096 float4
    int r = f >> 10, rem = f & 1023;
    int e = rem >> 3, kq = rem & 7;
    float4 v = *reinterpret_cast<const float4*>(
        &kfg[(size_t)((blkrow + r) * 128 + e) * 32 + kq * 4]);
    float* dst = &kfp[r * 4224 + e * 33 + kq * 4];
    dst[0] = v.x; dst[1] = v.y; dst[2] = v.z; dst[3] = v.w;
  }

  // register preloads: w_ih quarter (64 f32), w_hh quarter, bias. NO m2 in regs.
  float4 w4r[16];
  #pragma unroll
  for (int i4 = 0; i4 < 16; ++i4)
    w4r[i4] = *reinterpret_cast<const float4*>(&wih[g * 256 + sh * 64 + i4 * 4]);
  float whr[8];
  #pragma unroll
  for (int jk = 0; jk < 8; ++jk) whr[jk] = whh[g * 32 + sh * 8 + jk];
  const double bsum = (double)bih[g] + (double)bhh[g];
  const double vpbr = vpbg[o];

  // ---- mask load with dtype auto-detect (bool as u8 bytes vs 32-bit words) ----
  uint64_t m0, m1;
  {
    const uint32_t w0 = *(const uint32_t*)selmask;
    if (w0 == 0x01010101u){
      const uint8_t* m8 = (const uint8_t*)selmask;
      m0 = __ballot(m8[(blkrow + (w & 3)) * 128 + ln] != 0);
      m1 = __ballot(m8[(blkrow + (w & 3)) * 128 + 64 + ln] != 0);
    } else {
      const uint32_t* m32 = (const uint32_t*)selmask;
      m0 = __ballot(m32[(blkrow + (w & 3)) * 128 + ln] != 0);
      m1 = __ballot(m32[(blkrow + (w & 3)) * 128 + 64 + ln] != 0);
    }
  }
  bool  isend = false;
  float selnum = (float)NSTEPS;          // wave w<4, ln==0
  double cnt_reg = 0.0;                  // wave w<4, ln==0
  double c_reg = 0.0, sacc_reg = 0.0;    // wave w<4, lanes<32 (k=ln)
  if (t < 128) hf[t] = 0.f;
  __syncthreads();

  #pragma unroll 1
  for (int i = 0; i < NSTEPS; ++i){
    // --- A: x = relu(z) -> LDS (f32, reference's own quantization point) ---
    #pragma unroll
    for (int q = 0; q < 2; ++q){
      double zv = z[q];
      float xv = zv > 0.0 ? (float)zv : 0.0f;
      xk[(rh * 2 + q) * 288 + (o >> 5) * 36 + (o & 31)] = xv;
    }
    __syncthreads();                                  // bar1: xk ready

    // --- B: gates (all 8 waves; 1 gate x 64-d quarter; f32 chains, f64 combine) ---
    {
      float acc[4]  = {0.f,0.f,0.f,0.f};
      float hacc[4] = {0.f,0.f,0.f,0.f};
      #pragma unroll
      for (int i4 = 0; i4 < 16; ++i4){
        const int xi = (sh * 2 + (i4 >> 3)) * 36 + (i4 & 7) * 4;
        const float4 w4 = w4r[i4];
        #pragma unroll
        for (int r = 0; r < 4; ++r){
          float4 xv = *reinterpret_cast<const float4*>(&xk[r * 288 + xi]);
          acc[r] = fmaf(w4.x, xv.x, fmaf(w4.y, xv.y,
                   fmaf(w4.z, xv.z, fmaf(w4.w, xv.w, acc[r]))));
        }
      }
      #pragma unroll
      for (int q2 = 0; q2 < 2; ++q2){
        const float* wp = &whr[q2 * 4];
        #pragma unroll
        for (int r = 0; r < 4; ++r){
          float4 hv = *reinterpret_cast<const float4*>(&hf[r * 32 + sh * 8 + q2 * 4]);
          hacc[r] = fmaf(wp[0], hv.x, fmaf(wp[1], hv.y,
                    fmaf(wp[2], hv.z, fmaf(wp[3], hv.w, hacc[r]))));
        }
      }
      #pragma unroll
      for (int r = 0; r < 4; ++r){
        double tot = (double)acc[r] + (double)hacc[r];
        tot += __shfl_xor(tot, 1);
        tot += __shfl_xor(tot, 2);
        if (sh == 0) gl[r * 128 + g] = tot + bsum;
      }
    }
    __syncthreads();                                  // bar2: gl ready

    // --- waves 0..3: C/D/E/F for row w (wave-local; waves 4..7 go to bar3) ---
    if (w < 4){
      // C: LSTM pointwise (lanes<32; f64 internal, h published f32 — R4-validated)
      if (ln < 32){
        const int k = ln;
        double gi = gl[w * 128 + k],      gf = gl[w * 128 + 32 + k];
        double gc = gl[w * 128 + 64 + k], go = gl[w * 128 + 96 + k];
        double ig = 1.0 / (1.0 + exp(-gi));
        double fg = 1.0 / (1.0 + exp(-gf));
        double og = 1.0 / (1.0 + exp(-go));
        c_reg = fg * c_reg + ig * tanh(gc);
        hf[w * 32 + k] = (float)(og * tanh(c_reg));
      }
      asm volatile("s_waitcnt lgkmcnt(0)" ::: "memory");
      __builtin_amdgcn_sched_barrier(0);

      // D: logits (f64 split chains; pad-33 b32 reads conflict-free)
      double lg[2];
      const size_t lbase = ((size_t)(blkrow + w) * NSTEPS + i) * 128;
      #pragma unroll
      for (int j = 0; j < 2; ++j){
        const int e = ln + 64 * j;
        const float* kr = &kfp[w * 4224 + e * 33];
        double a0 = 0.0, a1 = 0.0;
        #pragma unroll
        for (int k4 = 0; k4 < 8; ++k4){
          float4 hv = *reinterpret_cast<const float4*>(&hf[w * 32 + k4 * 4]);  // uniform
          a0 = fma((double)kr[k4 * 4 + 0], (double)hv.x, a0);
          a1 = fma((double)kr[k4 * 4 + 1], (double)hv.y, a1);
          a0 = fma((double)kr[k4 * 4 + 2], (double)hv.z, a0);
          a1 = fma((double)kr[k4 * 4 + 3], (double)hv.w, a1);
        }
        lg[j] = a0 + a1;
        bool bit = (j == 0) ? ((m0 >> e) & 1ull) : ((m1 >> (e - 64)) & 1ull);
        outp[OUT_L0 + lbase + e] = bit ? (float)lg[j] : NEGV;
      }

      // E: gumbel-argmax (exact threefry; masked lanes can't win)
      double bs = -1.0e300; int bi = 1 << 20;
      {
        const uint2 kk = keys[i];
        #pragma unroll
        for (int j = 0; j < 2; ++j){
          const int e = ln + 64 * j;
          bool bit = (j == 0) ? ((m0 >> e) & 1ull) : ((m1 >> (e - 64)) & 1ull);
          if (bit){
            uint32_t bits = jax_bits(kk.x, kk.y, (uint32_t)((blkrow + w) * 128 + e));
            double sv = lg[j] + gumbel_bits(bits);
            if (sv > bs || (sv == bs && e < bi)){ bs = sv; bi = e; }
          }
        }
      }
      #pragma unroll
      for (int m = 1; m < 64; m <<= 1){
        double os = __shfl_xor(bs, m);
        int    oi = __shfl_xor(bi, m);
        if (os > bs || (os == bs && oi < bi)){ bs = os; bi = oi; }
      }
      const int uid = bi;

      // F: state updates (wave-local)
      {
        const bool new_end = (uid == 127);
        if (ln == 0 && new_end && !isend) selnum = (float)i;
        isend = isend || new_end;
        const double gate = isend ? 0.0 : 1.0;
        if (uid < 64) m0 &= ~(1ull << uid); else m1 &= ~(1ull << (uid - 64));
        if (ln == 0){
          gtf[w] = (float)gate;
          cnt_reg += gate;
          outp[OUT_U0 + (size_t)(blkrow + w) * NSTEPS + i] = (float)uid;
        }
        if (ln < 32){
          const int k = ln;
          float kv = kfp[w * 4224 + uid * 33 + k];
          double ov = (double)kv - kav[w * 32 + k];
          ovf[w * 32 + k] = (float)ov;
          sacc_reg += gate * ov;
        }
      }
    }
    __syncthreads();                                  // bar3: ovf/gtf ready

    // --- G: z += gate*(M2[o,:]·out + v_pb[o])  (f32 delta, f64 carry — R4-validated)
    //     m2 read from global each step: block footprint = 32 KB = L1-resident.
    //     Pointer laundering stops LICM from hoisting 32 VGPRs of m2 into the loop.
    {
      const float* mp = m2f + o * 32;
      asm volatile("" : "+v"(mp));      // opaque -> loads stay inside the loop
      float zf0 = 0.f, zf1 = 0.f;
      const int r0 = rh * 2, r1 = rh * 2 + 1;
      #pragma unroll
      for (int j8 = 0; j8 < 8; ++j8){
        float4 mr  = *reinterpret_cast<const float4*>(&mp[j8 * 4]);
        float4 ov0 = *reinterpret_cast<const float4*>(&ovf[r0 * 32 + j8 * 4]);  // uniform
        float4 ov1 = *reinterpret_cast<const float4*>(&ovf[r1 * 32 + j8 * 4]);  // uniform
        zf0 = fmaf(mr.x, ov0.x, fmaf(mr.y, ov0.y, fmaf(mr.z, ov0.z, fmaf(mr.w, ov0.w, zf0))));
        zf1 = fmaf(mr.x, ov1.x, fmaf(mr.y, ov1.y, fmaf(mr.z, ov1.z, fmaf(mr.w, ov1.w, zf1))));
      }
      if (gtf[r0] != 0.f) z[0] += (double)zf0 + vpbr;
      if (gtf[r1] != 0.f) z[1] += (double)zf1 + vpbr;
    }
    // no barrier: A(i+1) writes xk; all waves finished B(i) before bar2(i)<bar3(i).
  }

  // -------- epilogue: sel_num, s_acc publish, final ar --------
  __syncthreads();
  if (w < 4 && ln < 32) ovd[w * 32 + ln] = sacc_reg;
  if (w < 4 && ln == 0){
    cntd[w] = cnt_reg;
    outp[OUT_S0 + (blkrow + w)] = selnum;
  }
  __syncthreads();

  #pragma unroll
  for (int jj = 0; jj < 2; ++jj){
    const int dd = jj * 512 + t;
    float4 pw4[8];
    #pragma unroll
    for (int q = 0; q < 8; ++q)
      pw4[q] = *reinterpret_cast<const float4*>(&projw[dd * 32 + q * 4]);
    const double pb = (double)projb[dd];
    #pragma unroll
    for (int r = 0; r < 4; ++r){
      const double* sp = &ovd[r * 32];
      double acc = 0.0;
      #pragma unroll
      for (int q = 0; q < 8; ++q){
        acc = fma((double)pw4[q].x, sp[q * 4 + 0], acc);
        acc = fma((double)pw4[q].y, sp[q * 4 + 1], acc);
        acc = fma((double)pw4[q].z, sp[q * 4 + 2], acc);
        acc = fma((double)pw4[q].w, sp[q * 4 + 3], acc);
      }
      double arv = (double)ar0[(blkrow + r) * 1024 + dd] + acc + pb * cntd[r];
      outp[OUT_A0 + (size_t)(blkrow + r) * 1024 + dd] = (float)arv;
    }
  }
}

// ---------------- launcher ----------------
extern "C" void kernel_launch(void* const* d_in, const int* in_sizes, int n_in,
                              void* d_out, int out_size, void* d_ws, size_t ws_size,
                              hipStream_t stream){
  const float*   ar0   = (const float*)d_in[0];
  const float*   ee    = (const float*)d_in[1];
  const void*    msk   = (const void*)d_in[2];
  const float*   unum  = (const float*)d_in[3];
  const float*   convw = (const float*)d_in[4];
  const float*   convb = (const float*)d_in[5];
  const float*   fc1w  = (const float*)d_in[6];
  const float*   fc1b  = (const float*)d_in[7];
  const float*   wih   = (const float*)d_in[8];
  const float*   whh   = (const float*)d_in[9];
  const float*   bih   = (const float*)d_in[10];
  const float*   bhh   = (const float*)d_in[11];
  const float*   projw = (const float*)d_in[12];
  const float*   projb = (const float*)d_in[13];
  float* out = (float*)d_out;
  char*  ws  = (char*)d_ws;

  float*  kf  = (float*) (ws + WS_KF);
  double* ka  = (double*)(ws + WS_KA);
  float*  m2  = (float*) (ws + WS_M2);
  double* vpb = (double*)(ws + WS_VPB);

  k_keyfeat<<<2048, 256, 0, stream>>>(ee, convw, convb, kf);
  k_keyavg <<<512, 256, 0, stream>>>(kf, unum, ka);
  k_m2     <<<33, 256, 0, stream>>>(fc1w, projw, projb, m2, vpb);

  (void)hipFuncSetAttribute((const void*)k_scan,
                            hipFuncAttributeMaxDynamicSharedMemorySize, SM_SIZE);
  k_scan<<<1024, 512, SM_SIZE, stream>>>(ar0, msk, fc1w, fc1b, wih, whh, bih, bhh,
                                         projw, projb, kf, ka, m2, vpb, out);
}